// Round 11
// baseline (76.051 us; speedup 1.0000x reference)
//
#include <hip/hip_runtime.h>

// INT8QuantizedLinear: B=16, S=512, IN=1024, OUT=4096  (M=8192, N=4096, K=1024)
// Harness widens integer inputs: weight arrives as const int* (int32 per value).
// Round 11: PRODUCER-CONSUMER wave specialization (AITER mechanism). 128x128
// tile, BK=128, 5 waves: wave4 = producer (all staging + vmcnt(0), stall
// hidden), waves0-3 = consumers (read+MFMA only, NEVER wait vmcnt). One
// s_barrier per K-tile. LDS 64KB -> 2 blocks/CU at independent phases
// (cross-block read/MFMA overlap). All data-path pieces (swizzle, fragment
// map, epilogue) are the R3/R9-validated ones.

#define M_TOT 8192
#define N_TOT 4096
#define K_TOT 1024
#define QMAXF 127.0f

#define BM 128
#define BN 128
#define BK 128              // i8 elems per LDS K-tile (128 B rows)
#define NKT (K_TOT / BK)    // 8

typedef int i32x4 __attribute__((ext_vector_type(4)));

// ---------------------------------------------------------------------------
// Kernel 0: fused prep (quant blocks [0,8192), weight repack [8192,12288))
// ---------------------------------------------------------------------------
__global__ __launch_bounds__(256) void prep(const float* __restrict__ x,
                                            const int* __restrict__ w32,
                                            signed char* __restrict__ xq,
                                            signed char* __restrict__ w8,
                                            float* __restrict__ iscale) {
  const int b = blockIdx.x;
  const int t = threadIdx.x;

  if (b < M_TOT) {
    const float4 v = reinterpret_cast<const float4*>(x)[(size_t)b * 256 + t];
    float m = fmaxf(fmaxf(fabsf(v.x), fabsf(v.y)), fmaxf(fabsf(v.z), fabsf(v.w)));
#pragma unroll
    for (int off = 32; off >= 1; off >>= 1) m = fmaxf(m, __shfl_xor(m, off, 64));

    __shared__ float wmax[4];
    const int lane = t & 63, wid = t >> 6;
    if (lane == 0) wmax[wid] = m;
    __syncthreads();
    const float amax = fmaxf(fmaxf(wmax[0], wmax[1]), fmaxf(wmax[2], wmax[3]));

    float scale = amax / QMAXF;
    if (scale == 0.0f) scale = 1.0f;

    int qi;
    signed char* qb = reinterpret_cast<signed char*>(&qi);
    qb[0] = (signed char)(int)fminf(fmaxf(rintf(v.x / scale), -128.0f), 127.0f);
    qb[1] = (signed char)(int)fminf(fmaxf(rintf(v.y / scale), -128.0f), 127.0f);
    qb[2] = (signed char)(int)fminf(fmaxf(rintf(v.z / scale), -128.0f), 127.0f);
    qb[3] = (signed char)(int)fminf(fmaxf(rintf(v.w / scale), -128.0f), 127.0f);
    reinterpret_cast<int*>(xq)[(size_t)b * 256 + t] = qi;

    if (t == 0) iscale[b] = scale;
  } else {
    const int i = (b - M_TOT) * 256 + t;
    const int4 v = reinterpret_cast<const int4*>(w32)[i];
    const int packed = (v.x & 0xFF) | ((v.y & 0xFF) << 8) |
                       ((v.z & 0xFF) << 16) | (v.w << 24);
    reinterpret_cast<int*>(w8)[i] = packed;
  }
}

// ---------------------------------------------------------------------------
__device__ __forceinline__ void gload_lds16(const void* g, void* l) {
  __builtin_amdgcn_global_load_lds(
      (const __attribute__((address_space(1))) unsigned int*)g,
      (__attribute__((address_space(3))) unsigned int*)l, 16, 0, 0);
}

#define BARF asm volatile("s_barrier" ::: "memory")

__global__ __launch_bounds__(320, 2) void int8_gemm(const signed char* __restrict__ xq,
                                                    const signed char* __restrict__ w,
                                                    const float* __restrict__ iscale,
                                                    const float* __restrict__ wscale,
                                                    const float* __restrict__ bias,
                                                    float* __restrict__ out) {
  __shared__ __attribute__((aligned(16))) signed char As[2][BM][BK];  // 32 KiB
  __shared__ __attribute__((aligned(16))) signed char Bs[2][BN][BK];  // 32 KiB

  const int t = threadIdx.x;
  const int lane = t & 63;
  const int wid = t >> 6;   // 0..4: 4 = producer, 0..3 consumers

  // XCD chunking (R9-validated): 2048 blocks = 8 XCDs x 256; per XCD 16m x 16n
  // 128-tiles -> A-slice 2 MB + B-slice 2 MB resident in that XCD's L2.
  const int bid = blockIdx.x;
  const int xcd = bid & 7, li = bid >> 3;        // li 0..255
  const int mt = (xcd >> 1) * 16 + (li >> 4);    // 0..63
  const int nt = (xcd & 1) * 16 + (li & 15);     // 0..31
  const int m0 = mt * BM, n0 = nt * BN;

  if (wid == 4) {
    // ---------------- PRODUCER ----------------
    // one gload_lds = 64 lanes x 16 B = 1 KB = 8 rows of 128 B.
    // lane -> row srow = lane>>3, byte (lane&7)*16; row&7 == srow (srow<8),
    // so swizzled source col is constant per lane.
    const int srow = lane >> 3;                       // 0..7
    const int ssw = ((lane & 7) * 16) ^ (srow << 4);  // pre-swizzled source col

    auto stg = [&](int buf, int kt) {
      const int k0 = kt * BK;
#pragma unroll
      for (int c = 0; c < 16; ++c)
        gload_lds16(xq + (size_t)(m0 + c * 8 + srow) * K_TOT + k0 + ssw,
                    &As[buf][c * 8][0]);
#pragma unroll
      for (int c = 0; c < 16; ++c)
        gload_lds16(w + (size_t)(n0 + c * 8 + srow) * K_TOT + k0 + ssw,
                    &Bs[buf][c * 8][0]);
    };

    stg(0, 0);
    asm volatile("s_waitcnt vmcnt(0)" ::: "memory");
    BARF;  // bar_0: tile 0 ready
    for (int k2 = 0; k2 < NKT - 1; ++k2) {
      stg((k2 + 1) & 1, k2 + 1);                     // stage during window k2
      asm volatile("s_waitcnt vmcnt(0)" ::: "memory");  // hidden under consumers
      BARF;  // bar_{k2+1}: tile k2+1 ready, buf swap safe
    }
    return;  // producer: 8 barriers hit, exits
  }

  // ---------------- CONSUMERS (waves 0..3) ----------------
  const int wm = wid >> 1;  // 0..1
  const int wn = wid & 1;   // 0..1
  const int lr = lane & 15;
  const int kq = (lane >> 4) * 16;

  auto rdA = [&](int buf, int f, int ks) -> i32x4 {
    const int r = wm * 64 + f * 16 + lr;
    return *reinterpret_cast<const i32x4*>(&As[buf][r][(ks * 64 + kq) ^ ((r & 7) << 4)]);
  };
  auto rdB = [&](int buf, int g, int ks) -> i32x4 {
    const int r = wn * 64 + g * 16 + lr;
    return *reinterpret_cast<const i32x4*>(&Bs[buf][r][(ks * 64 + kq) ^ ((r & 7) << 4)]);
  };

  // preload epilogue scalars (overlaps producer's prologue stage)
  const int col = lane & 15;
  const int rq = lane >> 4;
  float wsc[4], bv[4];
#pragma unroll
  for (int g = 0; g < 4; ++g) {
    const int gn = n0 + wn * 64 + g * 16 + col;
    wsc[g] = wscale[gn];
    bv[g] = bias[gn];
  }
  float isc[4][4];
#pragma unroll
  for (int f = 0; f < 4; ++f)
#pragma unroll
    for (int i = 0; i < 4; ++i)
      isc[f][i] = iscale[m0 + wm * 64 + f * 16 + rq * 4 + i];

  i32x4 acc[4][4] = {};

  for (int k2 = 0; k2 < NKT; ++k2) {
    const int c = k2 & 1;
    BARF;  // bar_{k2}: tile k2 ready in buf c
    // read all 16 fragments, then 32 MFMAs — compiler interleaves with
    // fine-grained lgkmcnt; consumers never touch vmcnt.
    i32x4 a[4][2], b[4][2];
#pragma unroll
    for (int ks = 0; ks < 2; ++ks) {
#pragma unroll
      for (int f = 0; f < 4; ++f) a[f][ks] = rdA(c, f, ks);
#pragma unroll
      for (int g = 0; g < 4; ++g) b[g][ks] = rdB(c, g, ks);
    }
    __builtin_amdgcn_s_setprio(1);
#pragma unroll
    for (int ks = 0; ks < 2; ++ks)
#pragma unroll
      for (int f = 0; f < 4; ++f)
#pragma unroll
        for (int g = 0; g < 4; ++g)
          acc[f][g] = __builtin_amdgcn_mfma_i32_16x16x64_i8(a[f][ks], b[g][ks],
                                                            acc[f][g], 0, 0, 0);
    __builtin_amdgcn_s_setprio(0);
  }

  // ---- epilogue (validated R2/R9): col=lane&15, row=(lane>>4)*4+i;
  // g*16 stride -> 256 B contiguous per quarter-wave per row (full lines) ----
#pragma unroll
  for (int f = 0; f < 4; ++f) {
    const int gmb = m0 + wm * 64 + f * 16 + rq * 4;
#pragma unroll
    for (int i = 0; i < 4; ++i) {
      const int gm = gmb + i;
      float* rowp = out + (size_t)gm * N_TOT + n0 + wn * 64 + col;
#pragma unroll
      for (int g = 0; g < 4; ++g)
        rowp[g * 16] = (float)acc[f][g][i] * wsc[g] * isc[f][i] + bv[g];
    }
  }
}

// ---------------------------------------------------------------------------
extern "C" void kernel_launch(void* const* d_in, const int* in_sizes, int n_in,
                              void* d_out, int out_size, void* d_ws, size_t ws_size,
                              hipStream_t stream) {
  const float* x = (const float*)d_in[0];
  const int* w32 = (const int*)d_in[1];
  const float* wscale = (const float*)d_in[2];
  const float* bias = (const float*)d_in[3];
  float* out = (float*)d_out;

  signed char* xq = (signed char*)d_ws;                                    // 8 MB
  float* iscale = (float*)((char*)d_ws + (size_t)M_TOT * K_TOT);           // 32 KB
  signed char* w8 = (signed char*)((char*)d_ws + (size_t)M_TOT * K_TOT + M_TOT * 4);  // 4 MB

  const int pack_blocks = (N_TOT * K_TOT / 4) / 256;
  prep<<<M_TOT + pack_blocks, 256, 0, stream>>>(x, w32, xq, w8, iscale);
  int8_gemm<<<dim3((M_TOT / BM) * (N_TOT / BN)), 320, 0, stream>>>(xq, w8, iscale, wscale, bias, out);
}

// Round 12
// 67.224 us; speedup vs baseline: 1.1313x; 1.1313x over previous
//
#include <hip/hip_runtime.h>

// INT8QuantizedLinear: B=16, S=512, IN=1024, OUT=4096  (M=8192, N=4096, K=1024)
// Harness widens integer inputs: weight arrives as const int* (int32 per value).
// Round 12: clean occupancy A/B vs R9. Identical structure (128x128 tile,
// 4 waves, BK=64 dbuf, one __syncthreads per K-step, XCD chunking, validated
// swizzle/epilogue); ONLY changes: __launch_bounds__(256,3) (170-reg cap, no
// spill, 3 waves/SIMD -> 3 independent blocks/CU) and setprio removed.
// Mechanism: i8 MFMA and LDS-read are co-critical (1/64 B/op => 69 TB/s LDS
// at pipe peak); barrier-locked waves alternate the two pipes; independent
// co-resident blocks are the only source of read/MFMA overlap.

#define M_TOT 8192
#define N_TOT 4096
#define K_TOT 1024
#define QMAXF 127.0f

#define BM 128
#define BN 128
#define BK 64               // i8 elems per LDS K-step (64 B rows)
#define NKT (K_TOT / BK)    // 16

typedef int i32x4 __attribute__((ext_vector_type(4)));

// ---------------------------------------------------------------------------
// Kernel 0: fused prep (quant blocks [0,8192), weight repack [8192,12288))
// ---------------------------------------------------------------------------
__global__ __launch_bounds__(256) void prep(const float* __restrict__ x,
                                            const int* __restrict__ w32,
                                            signed char* __restrict__ xq,
                                            signed char* __restrict__ w8,
                                            float* __restrict__ iscale) {
  const int b = blockIdx.x;
  const int t = threadIdx.x;

  if (b < M_TOT) {
    const float4 v = reinterpret_cast<const float4*>(x)[(size_t)b * 256 + t];
    float m = fmaxf(fmaxf(fabsf(v.x), fabsf(v.y)), fmaxf(fabsf(v.z), fabsf(v.w)));
#pragma unroll
    for (int off = 32; off >= 1; off >>= 1) m = fmaxf(m, __shfl_xor(m, off, 64));

    __shared__ float wmax[4];
    const int lane = t & 63, wid = t >> 6;
    if (lane == 0) wmax[wid] = m;
    __syncthreads();
    const float amax = fmaxf(fmaxf(wmax[0], wmax[1]), fmaxf(wmax[2], wmax[3]));

    float scale = amax / QMAXF;
    if (scale == 0.0f) scale = 1.0f;

    int qi;
    signed char* qb = reinterpret_cast<signed char*>(&qi);
    qb[0] = (signed char)(int)fminf(fmaxf(rintf(v.x / scale), -128.0f), 127.0f);
    qb[1] = (signed char)(int)fminf(fmaxf(rintf(v.y / scale), -128.0f), 127.0f);
    qb[2] = (signed char)(int)fminf(fmaxf(rintf(v.z / scale), -128.0f), 127.0f);
    qb[3] = (signed char)(int)fminf(fmaxf(rintf(v.w / scale), -128.0f), 127.0f);
    reinterpret_cast<int*>(xq)[(size_t)b * 256 + t] = qi;

    if (t == 0) iscale[b] = scale;
  } else {
    const int i = (b - M_TOT) * 256 + t;
    const int4 v = reinterpret_cast<const int4*>(w32)[i];
    const int packed = (v.x & 0xFF) | ((v.y & 0xFF) << 8) |
                       ((v.z & 0xFF) << 16) | (v.w << 24);
    reinterpret_cast<int*>(w8)[i] = packed;
  }
}

// ---------------------------------------------------------------------------
__device__ __forceinline__ void gload_lds16(const void* g, void* l) {
  __builtin_amdgcn_global_load_lds(
      (const __attribute__((address_space(1))) unsigned int*)g,
      (__attribute__((address_space(3))) unsigned int*)l, 16, 0, 0);
}

__global__ __launch_bounds__(256, 3) void int8_gemm(const signed char* __restrict__ xq,
                                                    const signed char* __restrict__ w,
                                                    const float* __restrict__ iscale,
                                                    const float* __restrict__ wscale,
                                                    const float* __restrict__ bias,
                                                    float* __restrict__ out) {
  __shared__ __attribute__((aligned(16))) signed char As[2][BM][BK];  // 16 KiB
  __shared__ __attribute__((aligned(16))) signed char Bs[2][BN][BK];  // 16 KiB

  const int t = threadIdx.x;
  const int lane = t & 63;
  const int wid = t >> 6;   // 0..3
  const int wm = wid >> 1;  // 0..1 (64-row half)
  const int wn = wid & 1;   // 0..1 (64-col half)

  // XCD chunking (R9-validated): 2048 blocks = 8 XCDs x 256; per XCD 16m x 16n
  // 128-tiles -> A-slice 2 MB + B-slice 2 MB resident in that XCD's L2.
  const int bid = blockIdx.x;
  const int xcd = bid & 7, li = bid >> 3;        // li 0..255
  const int mt = (xcd >> 1) * 16 + (li >> 4);    // 0..63
  const int nt = (xcd & 1) * 16 + (li & 15);     // 0..31
  const int m0 = mt * BM, n0 = nt * BN;

  // staging: one call = 256 thr x 16 B = 4 KB = 64 rows of 64 B; linear LDS
  // dest, pre-swizzled global source. 64B-row involution: byte^(((row>>1)&3)<<4)
  // (R6/R9-validated, 0 bank conflicts measured).
  const int srow = t >> 2;                                         // 0..63
  const int scol_swz = ((t & 3) * 16) ^ (((srow >> 1) & 3) << 4);

  auto stage = [&](int buf, int kt) {
    const int k0 = kt * BK;
#pragma unroll
    for (int c = 0; c < 2; ++c) {
      gload_lds16(xq + (size_t)(m0 + c * 64 + srow) * K_TOT + k0 + scol_swz,
                  &As[buf][c * 64][0] + t * 16);
      gload_lds16(w + (size_t)(n0 + c * 64 + srow) * K_TOT + k0 + scol_swz,
                  &Bs[buf][c * 64][0] + t * 16);
    }
  };

  // fragment reads: row = base + f*16 + (lane&15), k-slice = (lane>>4)*16
  const int lr = lane & 15;
  const int kq = (lane >> 4) * 16;
  auto rdA = [&](int buf, int f) -> i32x4 {
    const int r = wm * 64 + f * 16 + lr;
    return *reinterpret_cast<const i32x4*>(&As[buf][r][kq ^ (((r >> 1) & 3) << 4)]);
  };
  auto rdB = [&](int buf, int g) -> i32x4 {
    const int r = wn * 64 + g * 16 + lr;
    return *reinterpret_cast<const i32x4*>(&Bs[buf][r][kq ^ (((r >> 1) & 3) << 4)]);
  };

  i32x4 acc[4][4] = {};

  stage(0, 0);
  __syncthreads();  // drain prologue stage

  for (int kt = 0; kt < NKT; ++kt) {
    const int cur = kt & 1;
    if (kt + 1 < NKT) stage(cur ^ 1, kt + 1);  // issue next-step loads first

    i32x4 a[4], b[4];
#pragma unroll
    for (int f = 0; f < 4; ++f) a[f] = rdA(cur, f);
#pragma unroll
    for (int g = 0; g < 4; ++g) b[g] = rdB(cur, g);

#pragma unroll
    for (int f = 0; f < 4; ++f)
#pragma unroll
      for (int g = 0; g < 4; ++g)
        acc[f][g] = __builtin_amdgcn_mfma_i32_16x16x64_i8(a[f], b[g], acc[f][g], 0, 0, 0);

    __syncthreads();  // single per-step drain: next tile landed, reads done
  }

  // ---- epilogue (validated R2-R11): col=lane&15, row=(lane>>4)*4+i ----
  const int col = lane & 15;
  const int rq = lane >> 4;
  float wsc[4], bv[4];
#pragma unroll
  for (int g = 0; g < 4; ++g) {
    const int gn = n0 + wn * 64 + g * 16 + col;
    wsc[g] = wscale[gn];
    bv[g] = bias[gn];
  }
#pragma unroll
  for (int f = 0; f < 4; ++f) {
    const int gmb = m0 + wm * 64 + f * 16 + rq * 4;
#pragma unroll
    for (int i = 0; i < 4; ++i) {
      const int gm = gmb + i;
      const float isc = iscale[gm];
      float* rowp = out + (size_t)gm * N_TOT + n0 + wn * 64 + col;
#pragma unroll
      for (int g = 0; g < 4; ++g)
        rowp[g * 16] = (float)acc[f][g][i] * wsc[g] * isc + bv[g];
    }
  }
}

// ---------------------------------------------------------------------------
extern "C" void kernel_launch(void* const* d_in, const int* in_sizes, int n_in,
                              void* d_out, int out_size, void* d_ws, size_t ws_size,
                              hipStream_t stream) {
  const float* x = (const float*)d_in[0];
  const int* w32 = (const int*)d_in[1];
  const float* wscale = (const float*)d_in[2];
  const float* bias = (const float*)d_in[3];
  float* out = (float*)d_out;

  signed char* xq = (signed char*)d_ws;                                    // 8 MB
  float* iscale = (float*)((char*)d_ws + (size_t)M_TOT * K_TOT);           // 32 KB
  signed char* w8 = (signed char*)((char*)d_ws + (size_t)M_TOT * K_TOT + M_TOT * 4);  // 4 MB

  const int pack_blocks = (N_TOT * K_TOT / 4) / 256;
  prep<<<M_TOT + pack_blocks, 256, 0, stream>>>(x, w32, xq, w8, iscale);
  int8_gemm<<<dim3((M_TOT / BM) * (N_TOT / BN)), 256, 0, stream>>>(xq, w8, iscale, wscale, bias, out);
}